// Round 1
// 428.285 us; speedup vs baseline: 1.0558x; 1.0558x over previous
//
#include <hip/hip_runtime.h>

#define H 1024
#define MMEM 4096
#define NTOK 8192
#define KTOP 64
#define FTHRESH 0.5f

typedef _Float16 half8 __attribute__((ext_vector_type(8)));  // 8 f16 in 4 VGPRs
typedef float vf4 __attribute__((ext_vector_type(4)));       // MFMA f32 acc

__device__ __forceinline__ short f2h(float x){
  union { _Float16 h; short s; } u; u.h = (_Float16)x; return u.s;
}
__device__ __forceinline__ float h2f(short s){
  union { _Float16 h; short s; } u; u.s = s; return (float)u.h;
}
// order-preserving float->uint32 key (monotone increasing)
__device__ __forceinline__ unsigned fkey_of(float x){
  unsigned u = __float_as_uint(x);
  return (u & 0x80000000u) ? ~u : (u | 0x80000000u);
}
__device__ __forceinline__ float val_of(unsigned k){
  unsigned u = (k & 0x80000000u) ? (k & 0x7fffffffu) : ~k;
  return __uint_as_float(u);
}

// async global->LDS, 16B/lane; LDS dest is wave-uniform base + lane*16 (HW rule)
__device__ __forceinline__ void gload_lds16(const short* g, short* l){
  __builtin_amdgcn_global_load_lds(
      (const __attribute__((address_space(1))) unsigned int*)g,
      (__attribute__((address_space(3))) unsigned int*)l, 16, 0, 0);
}

// ---------------- LayerNorm + surprise; outputs fp16 norm ----------------
__global__ __launch_bounds__(256) void ln_kernel(
    const float* __restrict__ hs, const float* __restrict__ g, const float* __restrict__ be,
    short* __restrict__ n16, float* __restrict__ surprise)
{
  int row = blockIdx.x, tid = threadIdx.x;
  long base = (long)row * H;
  float4 x = ((const float4*)(hs + base))[tid];
  float s1 = x.x + x.y + x.z + x.w;
  float s2 = x.x*x.x + x.y*x.y + x.z*x.z + x.w*x.w;
  __shared__ float r1[4], r2[4], r3[4];
  int w = tid >> 6, lane = tid & 63;
  for (int o = 32; o; o >>= 1){ s1 += __shfl_down(s1, o); s2 += __shfl_down(s2, o); }
  if (lane == 0){ r1[w] = s1; r2[w] = s2; }
  __syncthreads();
  float S1 = r1[0]+r1[1]+r1[2]+r1[3];
  float S2 = r2[0]+r2[1]+r2[2]+r2[3];
  float mean = S1 * (1.0f/H);
  float var  = S2 * (1.0f/H) - mean*mean;
  float rinv = rsqrtf(var + 1e-12f);
  float4 gg = ((const float4*)g)[tid];
  float4 bb = ((const float4*)be)[tid];
  float4 n;
  n.x = (x.x-mean)*rinv*gg.x + bb.x;
  n.y = (x.y-mean)*rinv*gg.y + bb.y;
  n.z = (x.z-mean)*rinv*gg.z + bb.z;
  n.w = (x.w-mean)*rinv*gg.w + bb.w;
  float sa = fabsf(n.x)+fabsf(n.y)+fabsf(n.z)+fabsf(n.w);
  for (int o = 32; o; o >>= 1) sa += __shfl_down(sa, o);
  if (lane == 0) r3[w] = sa;
  __syncthreads();
  if (tid == 0) surprise[row] = (r3[0]+r3[1]+r3[2]+r3[3]) * (1.0f/H);
  short4 h4;
  h4.x = f2h(n.x); h4.y = f2h(n.y); h4.z = f2h(n.z); h4.w = f2h(n.w);
  ((short4*)(n16 + base))[tid] = h4;
}

// ---------------- top-K level 1: per-256-chunk bitonic sort, emit top-64 ----------------
// blocks 0..31: surprise (max). blocks 32..47: importance (min, key inverted).
// packed = (key32 << 32) | (8191 - idx): desc order == (val desc, idx asc) == jax top_k.
__global__ __launch_bounds__(256) void topk_local(
    const float* __restrict__ surprise, const float* __restrict__ imp,
    unsigned long long* __restrict__ cand_s, unsigned long long* __restrict__ cand_i)
{
  __shared__ unsigned long long s[256];
  int b = blockIdx.x, tid = threadIdx.x;
  int maxmode = (b < 32);
  int gidx = maxmode ? (b*256 + tid) : ((b-32)*256 + tid);
  float x = maxmode ? surprise[gidx] : imp[gidx];
  unsigned k = fkey_of(x);
  if (!maxmode) k = ~k;
  s[tid] = ((unsigned long long)k << 32) | (unsigned)(8191 - gidx);
  __syncthreads();
  for (int kk = 2; kk <= 256; kk <<= 1)
    for (int j = kk >> 1; j > 0; j >>= 1){
      int i = tid, ixj = i ^ j;
      if (ixj > i){
        bool asc = ((i & kk) == 0);
        unsigned long long a = s[i], c = s[ixj];
        if ((a < c) == asc){ s[i] = c; s[ixj] = a; }   // descending overall
      }
      __syncthreads();
    }
  if (tid < 64){
    if (maxmode) cand_s[b*64 + tid] = s[tid];
    else         cand_i[(b-32)*64 + tid] = s[tid];
  }
}

// ---------------- top-K level 2: merge candidates via bitonic sort ----------------
// block 0: 2048 surprise candidates -> top_vals/top_idx. block 1: 1024 -> slots.
__global__ __launch_bounds__(256) void topk_merge(
    const unsigned long long* __restrict__ cand_s, const unsigned long long* __restrict__ cand_i,
    float* __restrict__ top_vals, int* __restrict__ top_idx, int* __restrict__ slots)
{
  __shared__ unsigned long long s[2048];
  int tid = threadIdx.x;
  int N = (blockIdx.x == 0) ? 2048 : 1024;
  const unsigned long long* src = (blockIdx.x == 0) ? cand_s : cand_i;
  for (int i = tid; i < N; i += 256) s[i] = src[i];
  __syncthreads();
  for (int kk = 2; kk <= N; kk <<= 1)
    for (int j = kk >> 1; j > 0; j >>= 1){
      for (int i = tid; i < N; i += 256){
        int ixj = i ^ j;
        if (ixj > i){
          bool asc = ((i & kk) == 0);
          unsigned long long a = s[i], c = s[ixj];
          if ((a < c) == asc){ s[i] = c; s[ixj] = a; }
        }
      }
      __syncthreads();
    }
  if (tid < 64){
    unsigned long long p = s[tid];
    int gi = 8191 - (int)(p & 0xffffffffu);
    if (blockIdx.x == 0){
      top_vals[tid] = val_of((unsigned)(p >> 32));
      top_idx[tid] = gi;
    } else {
      slots[tid] = gi;
    }
  }
}

// ---------------- fused prep: mem->m16+memT, Wq->hi/lo split (as-is layout), Wo->fp16 ----------------
__global__ __launch_bounds__(256) void prep_all_kernel(
    const float* __restrict__ mem, const float* __restrict__ Wq, const float* __restrict__ Wo,
    short* __restrict__ m16, short* __restrict__ memT,
    short* __restrict__ wq_h, short* __restrict__ wq_l, short* __restrict__ wo16)
{
  __shared__ __align__(16) short t[64][66];
  int b = blockIdx.x, tid = threadIdx.x;
  if (b < 1024){
    // mem fp32 64x64 tile -> m16 (row-major) + memT (transposed)
    int r0 = (b >> 4) * 64, c0 = (b & 15) * 64;
    #pragma unroll
    for (int k = 0; k < 4; ++k){
      int idx = k*256 + tid;
      int r = idx >> 4, c4 = (idx & 15) * 4;
      float4 x = *(const float4*)&mem[(long)(r0+r)*H + c0 + c4];
      short4 h;
      h.x = f2h(x.x); h.y = f2h(x.y); h.z = f2h(x.z); h.w = f2h(x.w);
      *(short4*)&m16[(long)(r0+r)*H + c0 + c4] = h;
      t[r][c4] = h.x; t[r][c4+1] = h.y; t[r][c4+2] = h.z; t[r][c4+3] = h.w;
    }
    __syncthreads();
    #pragma unroll
    for (int k = 0; k < 4; ++k){
      int idx = k*256 + tid;
      int c = idx >> 4, r4 = (idx & 15) * 4;
      short4 h;
      h.x = t[r4][c]; h.y = t[r4+1][c]; h.z = t[r4+2][c]; h.w = t[r4+3][c];
      *(short4*)&memT[(long)(c0+c)*MMEM + r0 + r4] = h;
    }
  } else if (b < 2048){
    // Wq elementwise fp16 hi/lo split, native [o][h] layout (B-operand of Q GEMM
    // contracts over its 2nd index = h, matching einsum "bsh,oh->bso")
    long i = (long)(b - 1024) * 256 + tid;
    float4 x = ((const float4*)Wq)[i];
    short4 h, l;
    h.x = f2h(x.x); l.x = f2h(x.x - h2f(h.x));
    h.y = f2h(x.y); l.y = f2h(x.y - h2f(h.y));
    h.z = f2h(x.z); l.z = f2h(x.z - h2f(h.z));
    h.w = f2h(x.w); l.w = f2h(x.w - h2f(h.w));
    ((short4*)wq_h)[i] = h;
    ((short4*)wq_l)[i] = l;
  } else {
    long i = (long)(b - 2048) * 256 + tid;
    float4 x = ((const float4*)Wo)[i];
    short4 h;
    h.x = f2h(x.x); h.y = f2h(x.y); h.z = f2h(x.z); h.w = f2h(x.w);
    ((short4*)wo16)[i] = h;
  }
}

// ---------------- top-K writes: recompute LN of selected rows, patch m16 + memT ----------------
__global__ __launch_bounds__(256) void update_kernel(
    const float* __restrict__ top_vals, const int* __restrict__ top_idx, const int* __restrict__ slots,
    const float* __restrict__ hs, const float* __restrict__ g, const float* __restrict__ be,
    short* __restrict__ m16, short* __restrict__ memT)
{
  int i = blockIdx.x;
  if (top_vals[i] <= FTHRESH) return;
  int s = slots[i], r = top_idx[i];
  int tid = threadIdx.x, w = tid >> 6, lane = tid & 63;
  long base = (long)r * H;
  float4 x = ((const float4*)(hs + base))[tid];
  float s1 = x.x + x.y + x.z + x.w;
  float s2 = x.x*x.x + x.y*x.y + x.z*x.z + x.w*x.w;
  __shared__ float r1[4], r2[4];
  for (int o = 32; o; o >>= 1){ s1 += __shfl_down(s1, o); s2 += __shfl_down(s2, o); }
  if (lane == 0){ r1[w] = s1; r2[w] = s2; }
  __syncthreads();
  float S1 = r1[0]+r1[1]+r1[2]+r1[3];
  float S2 = r2[0]+r2[1]+r2[2]+r2[3];
  float mean = S1 * (1.0f/H);
  float var  = S2 * (1.0f/H) - mean*mean;
  float rinv = rsqrtf(var + 1e-12f);
  float4 gg = ((const float4*)g)[tid];
  float4 bb = ((const float4*)be)[tid];
  short4 h4;
  h4.x = f2h((x.x-mean)*rinv*gg.x + bb.x);
  h4.y = f2h((x.y-mean)*rinv*gg.y + bb.y);
  h4.z = f2h((x.z-mean)*rinv*gg.z + bb.z);
  h4.w = f2h((x.w-mean)*rinv*gg.w + bb.w);
  ((short4*)(m16 + (long)s*H))[tid] = h4;
  long c4 = (long)tid * 4;
  memT[(c4+0)*MMEM + s] = h4.x;
  memT[(c4+1)*MMEM + s] = h4.y;
  memT[(c4+2)*MMEM + s] = h4.z;
  memT[(c4+3)*MMEM + s] = h4.w;
}

// ---------------- biasM[m] = bq . mem_upd[m] (reads patched m16) ----------------
__global__ __launch_bounds__(256) void bias_kernel(
    const float* __restrict__ bq, const short* __restrict__ m16, float* __restrict__ biasM)
{
  int tid = threadIdx.x, w = tid >> 6, lane = tid & 63;
  int m = blockIdx.x*4 + w;
  const short* ph = m16 + (long)m*H;
  float s = 0.f;
  for (int j = 0; j < 16; ++j){
    int h = lane + j*64;
    s += bq[h] * h2f(ph[h]);
  }
  for (int o = 32; o; o >>= 1) s += __shfl_down(s, o);
  if (lane == 0) biasM[m] = s;
}

// ---------------- 128x128-tile fp16 GEMM: C[M][N] = A[M][K] * B[N][K]^T ----------------
// m97 recipe (BK=64, global_load_lds w16, 2 barriers/K-block) + XOR-8 LDS swizzle
// (chunk pos ^= row&7 on global source AND ds_read side -> conflicts measured 0).
// XCD-aware bijective block swizzle: groups the column-blocks sharing an A panel
// onto one XCD's contiguous dispatch stream (lin%8 = XCD on MI355X) so the panel
// is fetched into that XCD's L2 once. Requires nwg%8==0 (all our grids qualify).
// SPLIT: 0 = A,B single f16 (1 MFMA); 2 = A single, B fp16 hi/lo (2 MFMA compensated).
// MODE 1: C+biasN -> fp16.  2: C -> fp16.  3: C+resid+biasN -> fp32.
template<int SPLIT, int MODE>
__global__ __launch_bounds__(256) void gemm128(
    const short* __restrict__ A,
    const short* __restrict__ Bh, const short* __restrict__ Bl,
    int K, int N,
    short* __restrict__ O1,
    float* __restrict__ Of, const float* __restrict__ resid, const float* __restrict__ biasN)
{
  __shared__ short sA[128*64];
  __shared__ short sBh[128*64];
  __shared__ short sBl[SPLIT ? 128*64 : 64];
  int tid = threadIdx.x, w = tid >> 6, lane = tid & 63, ln = lane & 15, quad = lane >> 4;
  int wr = w >> 1, wc = w & 1;
  // XCD swizzle (bijective since nwg%8==0)
  int nwgx = gridDim.x;
  int nwg  = nwgx * gridDim.y;
  int lin  = blockIdx.y * nwgx + blockIdx.x;
  int nl   = (lin & 7) * (nwg >> 3) + (lin >> 3);
  long m0 = (long)(nl / nwgx) * 128, n0 = (long)(nl % nwgx) * 128;
  long Kl = K;
  vf4 acc[4][4];
  #pragma unroll
  for (int i = 0; i < 4; ++i) for (int j = 0; j < 4; ++j) for (int r = 0; r < 4; ++r) acc[i][j][r] = 0.0f;

  for (long kk = 0; kk < Kl; kk += 64){
    #pragma unroll
    for (int j = 0; j < 4; ++j){
      int f = (w*4 + j)*64 + lane;            // 16B-chunk id in [0,1024)
      int row = f >> 3, c8 = f & 7;
      long go = kk + (long)((c8 ^ (row & 7)) * 8);   // XOR-swizzled source chunk
      gload_lds16(A  + (m0+row)*Kl + go, sA  + (w*4+j)*512);
      gload_lds16(Bh + (n0+row)*Kl + go, sBh + (w*4+j)*512);
      if (SPLIT) gload_lds16(Bl + (n0+row)*Kl + go, sBl + (w*4+j)*512);
    }
    __syncthreads();
    #pragma unroll
    for (int ks = 0; ks < 64; ks += 32){
      int cbase = (ks >> 3) + quad;
      half8 bh[4], bl[4];
      #pragma unroll
      for (int j = 0; j < 4; ++j){
        int rb = wc*64 + j*16 + ln;
        int cb = cbase ^ (rb & 7);
        bh[j] = *(const half8*)&sBh[rb*64 + cb*8];
        if (SPLIT) bl[j] = *(const half8*)&sBl[rb*64 + cb*8];
      }
      #pragma unroll
      for (int i = 0; i < 4; ++i){
        int ra = wr*64 + i*16 + ln;
        int ca = cbase ^ (ra & 7);
        half8 a = *(const half8*)&sA[ra*64 + ca*8];
        #pragma unroll
        for (int j = 0; j < 4; ++j){
          acc[i][j] = __builtin_amdgcn_mfma_f32_16x16x32_f16(a, bh[j], acc[i][j], 0, 0, 0);
          if (SPLIT)
            acc[i][j] = __builtin_amdgcn_mfma_f32_16x16x32_f16(a, bl[j], acc[i][j], 0, 0, 0);
        }
      }
    }
    __syncthreads();
  }

  #pragma unroll
  for (int i = 0; i < 4; ++i){
    #pragma unroll
    for (int j = 0; j < 4; ++j){
      #pragma unroll
      for (int r = 0; r < 4; ++r){
        long row = m0 + wr*64 + i*16 + quad*4 + r;   // C/D: row=quad*4+reg, col=lane&15
        long col = n0 + wc*64 + j*16 + ln;
        float v = acc[i][j][r];
        if (MODE == 1){
          O1[row*(long)N + col] = f2h(v + biasN[col]);
        } else if (MODE == 2){
          O1[row*(long)N + col] = f2h(v);
        } else {
          Of[row*(long)N + col] = v + resid[row*(long)N + col] + biasN[col];
        }
      }
    }
  }
}

// ---------------- row softmax in-place: sim fp16 [NTOK][MMEM] -> P fp16 ----------------
__global__ __launch_bounds__(256) void softmax_kernel(short* __restrict__ simP)
{
  long row = blockIdx.x;
  int tid = threadIdx.x, w = tid >> 6, lane = tid & 63;
  half8* ptr = (half8*)(simP + row*MMEM);
  float xf[16];
  float mx = -1e30f;
  #pragma unroll
  for (int j = 0; j < 2; ++j){
    half8 x = ptr[tid + j*256];
    #pragma unroll
    for (int e = 0; e < 8; ++e){ float f = (float)x[e]; xf[j*8+e] = f; mx = fmaxf(mx, f); }
  }
  for (int o = 32; o; o >>= 1) mx = fmaxf(mx, __shfl_xor(mx, o));
  __shared__ float rmax[4], rsum[4];
  if (lane == 0) rmax[w] = mx;
  __syncthreads();
  mx = fmaxf(fmaxf(rmax[0], rmax[1]), fmaxf(rmax[2], rmax[3]));
  float p[16], s = 0.f;
  #pragma unroll
  for (int k = 0; k < 16; ++k){ p[k] = __expf(xf[k] - mx); s += p[k]; }
  for (int o = 32; o; o >>= 1) s += __shfl_xor(s, o);
  if (lane == 0) rsum[w] = s;
  __syncthreads();
  float inv = 1.0f / (rsum[0]+rsum[1]+rsum[2]+rsum[3]);
  #pragma unroll
  for (int j = 0; j < 2; ++j){
    half8 o8;
    #pragma unroll
    for (int e = 0; e < 8; ++e) o8[e] = (_Float16)(p[j*8+e] * inv);
    ptr[tid + j*256] = o8;
  }
}

extern "C" void kernel_launch(void* const* d_in, const int* in_sizes, int n_in,
                              void* d_out, int out_size, void* d_ws, size_t ws_size,
                              hipStream_t stream)
{
  const float* hs  = (const float*)d_in[0];
  const float* gam = (const float*)d_in[1];
  const float* bet = (const float*)d_in[2];
  const float* Wq  = (const float*)d_in[3];
  const float* bq  = (const float*)d_in[4];
  const float* Wo  = (const float*)d_in[5];
  const float* bo  = (const float*)d_in[6];
  const float* mem = (const float*)d_in[7];
  const float* imp = (const float*)d_in[8];
  float* out = (float*)d_out;

  char* ws = (char*)d_ws;
  short* n16   = (short*)(ws);                   // [0,16)   fp16 norm
  short* q16   = (short*)(ws + (16ull<<20));     // [16,32)  fp16 Q = norm@Wq^T
  short* m16   = (short*)(ws + (32ull<<20));     // [32,40)  fp16 mem (patched)
  short* memT  = (short*)(ws + (40ull<<20));     // [40,48)  mem_upd^T fp16 (patched)
  short* simP  = (short*)(ws + (48ull<<20));     // [48,112) fp16 logits, softmax in-place -> P
  short* vwoT  = (short*)(ws + (112ull<<20));    // [112,120) fp16 VWoT[o][m] = (mem_upd @ Wo^T)^T
  short* wq_h  = (short*)(ws + (128ull<<20));    // [128,130) Wq fp16 hi, native [o][h]
  short* wq_l  = (short*)(ws + (130ull<<20));    // [130,132) Wq fp16 lo
  short* wo16  = (short*)(ws + (132ull<<20));    // [132,134)
  char*  tail  = ws + (134ull<<20);
  float* biasM    = (float*)tail;
  float* surprise = (float*)(tail + (64<<10));
  float* top_vals = (float*)(tail + (128<<10));
  int*   top_idx  = (int*)  (tail + (129<<10));
  int*   slots    = (int*)  (tail + (130<<10));
  unsigned long long* cand_s = (unsigned long long*)(tail + (132<<10));  // 16 KB
  unsigned long long* cand_i = (unsigned long long*)(tail + (148<<10));  // 8 KB

  ln_kernel<<<NTOK, 256, 0, stream>>>(hs, gam, bet, n16, surprise);
  topk_local<<<48, 256, 0, stream>>>(surprise, imp, cand_s, cand_i);
  topk_merge<<<2, 256, 0, stream>>>(cand_s, cand_i, top_vals, top_idx, slots);
  prep_all_kernel<<<3072, 256, 0, stream>>>(mem, Wq, Wo, m16, memT, wq_h, wq_l, wo16);
  update_kernel<<<KTOP, 256, 0, stream>>>(top_vals, top_idx, slots, hs, gam, bet, m16, memT);
  bias_kernel<<<1024, 256, 0, stream>>>(bq, m16, biasM);
  // VWoT[o][m] = Wo[o][:] . mem_upd[m][:]  (A=wo16 [1024][1024], B=m16 [4096][1024])
  // -> out = P @ VWoT^T replaces (P@V)@Wo^T: deletes the retr GEMM + retr buffer.
  gemm128<0,2><<<dim3(32,8), 256, 0, stream>>>(
      wo16, m16, m16, H, MMEM, vwoT, nullptr, nullptr, nullptr);
  // Q = norm @ Wq^T  (B = Wq native layout, split hi/lo), out fp16
  gemm128<2,2><<<dim3(8,64), 256, 0, stream>>>(
      n16, wq_h, wq_l, H, H, q16, nullptr, nullptr, nullptr);
  // sim = Q @ m16^T + biasM  (plain f16, 1 MFMA/elem), out fp16
  gemm128<0,1><<<dim3(32,64), 256, 0, stream>>>(
      q16, m16, m16, H, MMEM, simP, nullptr, nullptr, biasM);
  // softmax rows in-place -> P fp16 (normalized)
  softmax_kernel<<<NTOK, 256, 0, stream>>>(simP);
  // out = hidden + P @ VWoT^T + bo   (fused retr+output projection)
  gemm128<0,3><<<dim3(8,64), 256, 0, stream>>>(
      simP, vwoT, vwoT, MMEM, H, nullptr, out, hs, bo);
}